// Round 1
// baseline (227.675 us; speedup 1.0000x reference)
//
#include <hip/hip_runtime.h>
#include <hip/hip_bf16.h>
#include <stdint.h>
#include <math.h>

// CausalMultiheadRoPEAttn: B=2, S=2048, D=1024, H=16, Dh=64
// Pipeline: prep (bf16 casts + rope table) -> fused QKV gemm (+bias+rope, V
// stored transposed) -> flash attention (bf16 MFMA, online softmax) -> out gemm.
// Workspace layout (bytes):
//   ctab   @ 0         (2048*32*4   = 262144)
//   stab   @ 262144    (262144)
//   Xb     @ 524288    (4096*1024*2 = 8388608)   bf16 input
//   Wqb    @ 8912896   (1024*1024*2 = 2097152)
//   Wkb    @ 11010048
//   Wvb    @ 13107200
//   Wob    @ 15204352
//   Qb     @ 17301504  ([b][h][s][d] bf16, rope'd, *0.125)
//   Kb     @ 25690112  ([b][h][s][d] bf16, rope'd)
//   Vtb    @ 34078720  ([b][h][d][s] bf16, transposed)
//   AO     @ 42467328  ([m][1024] bf16 attention output)
//   total 50855936 bytes

typedef __bf16 bf16;
typedef __attribute__((ext_vector_type(4))) __bf16 bf16x4;
typedef __attribute__((ext_vector_type(8))) __bf16 bf16x8;
typedef __attribute__((ext_vector_type(4))) float f32x4;

#define SEQN 2048
#define DMOD 1024
#define NHEAD 16
#define DHEAD 64
#define MTOT 4096
#define ATT_SCALE 0.125f

__device__ __forceinline__ void gload_lds16(const bf16* g, bf16* l) {
  __builtin_amdgcn_global_load_lds(
      (const __attribute__((address_space(1))) uint32_t*)g,
      (__attribute__((address_space(3))) uint32_t*)l,
      16, 0, 0);
}

// ---------------------------------------------------------------- prep
__global__ __launch_bounds__(256) void prep_kernel(
    const float* __restrict__ X,
    const float* __restrict__ Wq, const float* __restrict__ Wk,
    const float* __restrict__ Wv, const float* __restrict__ Wo,
    bf16* __restrict__ Xb, bf16* __restrict__ Wqb, bf16* __restrict__ Wkb,
    bf16* __restrict__ Wvb, bf16* __restrict__ Wob,
    float* __restrict__ ctab, float* __restrict__ stab)
{
  const int tid = blockIdx.x * blockDim.x + threadIdx.x;
  const int nth = gridDim.x * blockDim.x;

  const float4* X4 = (const float4*)X;
  for (int i = tid; i < MTOT * DMOD / 4; i += nth) {
    float4 v = X4[i];
    bf16x4 o = { (bf16)v.x, (bf16)v.y, (bf16)v.z, (bf16)v.w };
    *(bf16x4*)(Xb + (size_t)i * 4) = o;
  }
  const float4* q4 = (const float4*)Wq;
  const float4* k4 = (const float4*)Wk;
  const float4* v4 = (const float4*)Wv;
  const float4* o4 = (const float4*)Wo;
  for (int i = tid; i < DMOD * DMOD / 4; i += nth) {
    float4 a = q4[i];
    float4 b = k4[i];
    float4 c = v4[i];
    float4 d = o4[i];
    *(bf16x4*)(Wqb + (size_t)i * 4) = bf16x4{ (bf16)a.x, (bf16)a.y, (bf16)a.z, (bf16)a.w };
    *(bf16x4*)(Wkb + (size_t)i * 4) = bf16x4{ (bf16)b.x, (bf16)b.y, (bf16)b.z, (bf16)b.w };
    *(bf16x4*)(Wvb + (size_t)i * 4) = bf16x4{ (bf16)c.x, (bf16)c.y, (bf16)c.z, (bf16)c.w };
    *(bf16x4*)(Wob + (size_t)i * 4) = bf16x4{ (bf16)d.x, (bf16)d.y, (bf16)d.z, (bf16)d.w };
  }
  for (int i = tid; i < SEQN * 32; i += nth) {
    const int s = i >> 5, p = i & 31;
    const float invf = (float)pow(10000.0, -(double)p / 32.0);
    const float ang = (float)s * invf;   // replicate ref's f32 s*inv_freq
    float sv, cv;
    sincosf(ang, &sv, &cv);
    ctab[i] = cv;
    stab[i] = sv;
  }
}

// ---------------------------------------------------------------- QKV gemm
// C[m][n] = X[m][:] . W[n][:]  (both k-contiguous), 128x128 tile, BK=32.
__global__ __launch_bounds__(256) void gemm_qkv(
    const bf16* __restrict__ Xb,
    const bf16* __restrict__ Wqb, const bf16* __restrict__ Wkb, const bf16* __restrict__ Wvb,
    const float* __restrict__ bq, const float* __restrict__ bk, const float* __restrict__ bv,
    const float* __restrict__ ctab, const float* __restrict__ stab,
    bf16* __restrict__ Qb, bf16* __restrict__ Kb, bf16* __restrict__ Vtb)
{
  __shared__ bf16 sA[128 * 32];
  __shared__ bf16 sB[128 * 32];

  const int z = blockIdx.z;
  const bf16* Bm = (z == 0) ? Wqb : (z == 1) ? Wkb : Wvb;
  const float* bias = (z == 0) ? bq : (z == 1) ? bk : bv;

  const int t = threadIdx.x;
  const int lane = t & 63, l15 = lane & 15, g = lane >> 4;
  const int wave = t >> 6, wm = wave >> 1, wn = wave & 1;
  const int tileM = blockIdx.y * 128, tileN = blockIdx.x * 128;

  f32x4 acc[4][4] = {};

  const int srow = t >> 2, schk = t & 3;
  const bf16* gA = Xb + (size_t)(tileM + srow) * DMOD + schk * 8;
  const bf16* gB = Bm + (size_t)(tileN + srow) * DMOD + schk * 8;
  bf16* lA = sA + t * 8;
  bf16* lB = sB + t * 8;

  for (int k0 = 0; k0 < DMOD; k0 += 32) {
    __syncthreads();
    gload_lds16(gA + k0, lA);
    gload_lds16(gA + k0 + 64 * DMOD, lA + 2048);
    gload_lds16(gB + k0, lB);
    gload_lds16(gB + k0 + 64 * DMOD, lB + 2048);
    __syncthreads();
    bf16x8 af[4], bfr[4];
#pragma unroll
    for (int i = 0; i < 4; ++i)
      af[i] = *(const bf16x8*)(sA + (wm * 64 + i * 16 + l15) * 32 + g * 8);
#pragma unroll
    for (int j = 0; j < 4; ++j)
      bfr[j] = *(const bf16x8*)(sB + (wn * 64 + j * 16 + l15) * 32 + g * 8);
#pragma unroll
    for (int i = 0; i < 4; ++i)
#pragma unroll
      for (int j = 0; j < 4; ++j)
        acc[i][j] = __builtin_amdgcn_mfma_f32_16x16x32_bf16(af[i], bfr[j], acc[i][j], 0, 0, 0);
  }

  // epilogue: bias (+rope for q/k, scale for q), store bf16.
#pragma unroll
  for (int j = 0; j < 4; ++j) {
    const int col = tileN + wn * 64 + j * 16 + l15;
    const float bcol = bias[col];
    const int h = col >> 6, d = col & 63;
#pragma unroll
    for (int i = 0; i < 4; ++i) {
#pragma unroll
      for (int r = 0; r < 4; ++r) {
        const int row = tileM + wm * 64 + i * 16 + g * 4 + r;
        const int b = row >> 11, s = row & (SEQN - 1);
        const float v = acc[i][j][r] + bcol;
        if (z != 2) {
          const int pair = d >> 1;
          const float cv = ctab[s * 32 + pair];
          const float sv = stab[s * 32 + pair];
          const float partner = __shfl_xor(v, 1);
          // even d: x_e*c - x_o*s ; odd d: x_e*s + x_o*c (partner is the mate)
          float rv = (d & 1) ? (partner * sv + v * cv) : (v * cv - partner * sv);
          if (z == 0) rv *= ATT_SCALE;
          bf16* dst = (z == 0) ? Qb : Kb;
          dst[(((size_t)(b * NHEAD + h)) * SEQN + s) * DHEAD + d] = (bf16)rv;
        } else {
          Vtb[(((size_t)(b * NHEAD + h)) * DHEAD + d) * SEQN + s] = (bf16)v;
        }
      }
    }
  }
}

// ---------------------------------------------------------------- attention
// grid (32 qtiles, 32 bh); 4 waves x 16 q-rows; KVBLK=64; online softmax.
__global__ __launch_bounds__(256) void attn_kernel(
    const bf16* __restrict__ Qb, const bf16* __restrict__ Kb,
    const bf16* __restrict__ Vt, bf16* __restrict__ AO)
{
  __shared__ bf16 sK[64 * 72];
  __shared__ bf16 sV[64 * 72];
  __shared__ bf16 sP[4][16 * 72];

  const int t = threadIdx.x;
  const int lane = t & 63, l15 = lane & 15, g = lane >> 4;
  const int wave = t >> 6;
  const int qtile = 31 - blockIdx.x;       // heavy tiles dispatch first
  const int bh = blockIdx.y;
  const int q0 = qtile * 64;
  const int qbase = q0 + wave * 16;
  const size_t kbase = (size_t)bh * SEQN * DHEAD;  // Q,K base
  const size_t vbase = (size_t)bh * DHEAD * SEQN;  // Vt base

  bf16x8 aq[2];
#pragma unroll
  for (int kc = 0; kc < 2; ++kc)
    aq[kc] = *(const bf16x8*)(Qb + kbase + (size_t)(qbase + l15) * DHEAD + kc * 32 + g * 8);

  f32x4 acco[4] = {};
  float mrow[4], lrow[4];
#pragma unroll
  for (int r = 0; r < 4; ++r) { mrow[r] = -1e30f; lrow[r] = 0.f; }

  const int kvend = q0 + 64;
  for (int kv0 = 0; kv0 < kvend; kv0 += 64) {
    __syncthreads();   // previous iteration's LDS readers done
    {
      const int row0 = t >> 3, chk = t & 7;          // 32 rows per round
#pragma unroll
      for (int i = 0; i < 2; ++i) {
        const int row = row0 + i * 32;
        bf16x8 kvv = *(const bf16x8*)(Kb + kbase + (size_t)(kv0 + row) * DHEAD + chk * 8);
        bf16x8 vvv = *(const bf16x8*)(Vt + vbase + (size_t)row * SEQN + kv0 + chk * 8);
        *(bf16x8*)(sK + row * 72 + chk * 8) = kvv;
        *(bf16x8*)(sV + row * 72 + chk * 8) = vvv;
      }
    }
    __syncthreads();   // staging visible

    // scores: sc[j] = Q . K^T for key subtile j
    f32x4 sc[4] = {};
#pragma unroll
    for (int j = 0; j < 4; ++j)
#pragma unroll
      for (int kc = 0; kc < 2; ++kc) {
        bf16x8 bk = *(const bf16x8*)(sK + (j * 16 + l15) * 72 + kc * 32 + g * 8);
        sc[j] = __builtin_amdgcn_mfma_f32_16x16x32_bf16(aq[kc], bk, sc[j], 0, 0, 0);
      }

    // causal mask + online softmax (rows g*4+r, cols j*16+l15)
    float p[4][4];
#pragma unroll
    for (int r = 0; r < 4; ++r) {
      const int qg = qbase + g * 4 + r;
      float tm = -3e38f;
#pragma unroll
      for (int j = 0; j < 4; ++j) {
        const int kg = kv0 + j * 16 + l15;
        const float s = (kg <= qg) ? sc[j][r] : -1e30f;
        sc[j][r] = s;
        tm = fmaxf(tm, s);
      }
      tm = fmaxf(tm, __shfl_xor(tm, 1));
      tm = fmaxf(tm, __shfl_xor(tm, 2));
      tm = fmaxf(tm, __shfl_xor(tm, 4));
      tm = fmaxf(tm, __shfl_xor(tm, 8));
      const float mnew = fmaxf(mrow[r], tm);
      const float alpha = __expf(mrow[r] - mnew);
      mrow[r] = mnew;
      float rs = 0.f;
#pragma unroll
      for (int j = 0; j < 4; ++j) {
        const float pv = __expf(sc[j][r] - mnew);
        p[j][r] = pv;
        rs += pv;
      }
      rs += __shfl_xor(rs, 1);
      rs += __shfl_xor(rs, 2);
      rs += __shfl_xor(rs, 4);
      rs += __shfl_xor(rs, 8);
      lrow[r] = lrow[r] * alpha + rs;
#pragma unroll
      for (int j = 0; j < 4; ++j) acco[j][r] *= alpha;
    }

    // P -> per-wave LDS (C-layout -> A-frag layout transpose)
#pragma unroll
    for (int r = 0; r < 4; ++r)
#pragma unroll
      for (int j = 0; j < 4; ++j)
        sP[wave][(g * 4 + r) * 72 + j * 16 + l15] = (bf16)p[j][r];
    __syncthreads();   // (also guarantees P writes visible before reads)

    bf16x8 pa[2];
#pragma unroll
    for (int kc = 0; kc < 2; ++kc)
      pa[kc] = *(const bf16x8*)(&sP[wave][l15 * 72 + kc * 32 + g * 8]);
#pragma unroll
    for (int j = 0; j < 4; ++j)
#pragma unroll
      for (int kc = 0; kc < 2; ++kc) {
        bf16x8 bv = *(const bf16x8*)(sV + (j * 16 + l15) * 72 + kc * 32 + g * 8);
        acco[j] = __builtin_amdgcn_mfma_f32_16x16x32_bf16(pa[kc], bv, acco[j], 0, 0, 0);
      }
  }

  const int b = bh >> 4, h = bh & 15;
#pragma unroll
  for (int j = 0; j < 4; ++j)
#pragma unroll
    for (int r = 0; r < 4; ++r) {
      const int q = qbase + g * 4 + r;
      const int dd = j * 16 + l15;
      const float v = acco[j][r] / lrow[r];
      AO[((size_t)(b * SEQN + q)) * DMOD + h * DHEAD + dd] = (bf16)v;
    }
}

// ---------------------------------------------------------------- out gemm
__global__ __launch_bounds__(256) void gemm_out(
    const bf16* __restrict__ AO, const bf16* __restrict__ Wob,
    const float* __restrict__ bo, float* __restrict__ out)
{
  __shared__ bf16 sA[128 * 32];
  __shared__ bf16 sB[128 * 32];

  const int t = threadIdx.x;
  const int lane = t & 63, l15 = lane & 15, g = lane >> 4;
  const int wave = t >> 6, wm = wave >> 1, wn = wave & 1;
  const int tileM = blockIdx.y * 128, tileN = blockIdx.x * 128;

  f32x4 acc[4][4] = {};

  const int srow = t >> 2, schk = t & 3;
  const bf16* gA = AO + (size_t)(tileM + srow) * DMOD + schk * 8;
  const bf16* gB = Wob + (size_t)(tileN + srow) * DMOD + schk * 8;
  bf16* lA = sA + t * 8;
  bf16* lB = sB + t * 8;

  for (int k0 = 0; k0 < DMOD; k0 += 32) {
    __syncthreads();
    gload_lds16(gA + k0, lA);
    gload_lds16(gA + k0 + 64 * DMOD, lA + 2048);
    gload_lds16(gB + k0, lB);
    gload_lds16(gB + k0 + 64 * DMOD, lB + 2048);
    __syncthreads();
    bf16x8 af[4], bfr[4];
#pragma unroll
    for (int i = 0; i < 4; ++i)
      af[i] = *(const bf16x8*)(sA + (wm * 64 + i * 16 + l15) * 32 + g * 8);
#pragma unroll
    for (int j = 0; j < 4; ++j)
      bfr[j] = *(const bf16x8*)(sB + (wn * 64 + j * 16 + l15) * 32 + g * 8);
#pragma unroll
    for (int i = 0; i < 4; ++i)
#pragma unroll
      for (int j = 0; j < 4; ++j)
        acc[i][j] = __builtin_amdgcn_mfma_f32_16x16x32_bf16(af[i], bfr[j], acc[i][j], 0, 0, 0);
  }

#pragma unroll
  for (int j = 0; j < 4; ++j) {
    const int col = tileN + wn * 64 + j * 16 + l15;
    const float bcol = bo[col];
#pragma unroll
    for (int i = 0; i < 4; ++i)
#pragma unroll
      for (int r = 0; r < 4; ++r) {
        const int row = tileM + wm * 64 + i * 16 + g * 4 + r;
        out[(size_t)row * DMOD + col] = acc[i][j][r] + bcol;
      }
  }
}

// ---------------------------------------------------------------- launch
extern "C" void kernel_launch(void* const* d_in, const int* in_sizes, int n_in,
                              void* d_out, int out_size, void* d_ws, size_t ws_size,
                              hipStream_t stream)
{
  (void)in_sizes; (void)n_in; (void)out_size; (void)ws_size;
  const float* X  = (const float*)d_in[0];
  const float* Wq = (const float*)d_in[1];
  const float* bq = (const float*)d_in[2];
  const float* Wk = (const float*)d_in[3];
  const float* bk = (const float*)d_in[4];
  const float* Wv = (const float*)d_in[5];
  const float* bv = (const float*)d_in[6];
  const float* Wo = (const float*)d_in[7];
  const float* bo = (const float*)d_in[8];

  char* ws = (char*)d_ws;
  float* ctab = (float*)(ws + 0);
  float* stab = (float*)(ws + 262144);
  bf16* Xb  = (bf16*)(ws + 524288);
  bf16* Wqb = (bf16*)(ws + 8912896);
  bf16* Wkb = (bf16*)(ws + 11010048);
  bf16* Wvb = (bf16*)(ws + 13107200);
  bf16* Wob = (bf16*)(ws + 15204352);
  bf16* Qb  = (bf16*)(ws + 17301504);
  bf16* Kb  = (bf16*)(ws + 25690112);
  bf16* Vtb = (bf16*)(ws + 34078720);
  bf16* AO  = (bf16*)(ws + 42467328);

  prep_kernel<<<1024, 256, 0, stream>>>(X, Wq, Wk, Wv, Wo, Xb, Wqb, Wkb, Wvb, Wob, ctab, stab);
  gemm_qkv<<<dim3(8, 32, 3), 256, 0, stream>>>(Xb, Wqb, Wkb, Wvb, bq, bk, bv, ctab, stab, Qb, Kb, Vtb);
  attn_kernel<<<dim3(32, 32), 256, 0, stream>>>(Qb, Kb, Vtb, AO);
  gemm_out<<<dim3(8, 32), 256, 0, stream>>>(AO, Wob, bo, (float*)d_out);
}

// Round 2
// 226.980 us; speedup vs baseline: 1.0031x; 1.0031x over previous
//
#include <hip/hip_runtime.h>
#include <hip/hip_bf16.h>
#include <stdint.h>
#include <math.h>

// CausalMultiheadRoPEAttn: B=2, S=2048, D=1024, H=16, Dh=64
// prep (bf16 casts + rope table) -> fused QKV gemm (+bias+rope, V transposed)
// -> barrier-free flash attention (direct-L2 B-frags, per-wave P LDS)
// -> out gemm.

typedef __bf16 bf16;
typedef __attribute__((ext_vector_type(4))) __bf16 bf16x4;
typedef __attribute__((ext_vector_type(8))) __bf16 bf16x8;
typedef __attribute__((ext_vector_type(4))) float f32x4;

#define SEQN 2048
#define DMOD 1024
#define NHEAD 16
#define DHEAD 64
#define MTOT 4096
// 0.125 * log2(e): scores land in log2 domain -> softmax uses exp2
#define QSCALE_LOG2E 0.18033688011112042f

__device__ __forceinline__ void gload_lds16(const bf16* g, bf16* l) {
  __builtin_amdgcn_global_load_lds(
      (const __attribute__((address_space(1))) uint32_t*)g,
      (__attribute__((address_space(3))) uint32_t*)l,
      16, 0, 0);
}

// ---------------------------------------------------------------- prep
__global__ __launch_bounds__(256) void prep_kernel(
    const float* __restrict__ X,
    const float* __restrict__ Wq, const float* __restrict__ Wk,
    const float* __restrict__ Wv, const float* __restrict__ Wo,
    bf16* __restrict__ Xb, bf16* __restrict__ Wqb, bf16* __restrict__ Wkb,
    bf16* __restrict__ Wvb, bf16* __restrict__ Wob,
    float* __restrict__ ctab, float* __restrict__ stab)
{
  const int tid = blockIdx.x * blockDim.x + threadIdx.x;
  const int nth = gridDim.x * blockDim.x;

  const float4* X4 = (const float4*)X;
  for (int i = tid; i < MTOT * DMOD / 4; i += nth) {
    float4 v = X4[i];
    bf16x4 o = { (bf16)v.x, (bf16)v.y, (bf16)v.z, (bf16)v.w };
    *(bf16x4*)(Xb + (size_t)i * 4) = o;
  }
  const float4* q4 = (const float4*)Wq;
  const float4* k4 = (const float4*)Wk;
  const float4* v4 = (const float4*)Wv;
  const float4* o4 = (const float4*)Wo;
  for (int i = tid; i < DMOD * DMOD / 4; i += nth) {
    float4 a = q4[i];
    float4 b = k4[i];
    float4 c = v4[i];
    float4 d = o4[i];
    *(bf16x4*)(Wqb + (size_t)i * 4) = bf16x4{ (bf16)a.x, (bf16)a.y, (bf16)a.z, (bf16)a.w };
    *(bf16x4*)(Wkb + (size_t)i * 4) = bf16x4{ (bf16)b.x, (bf16)b.y, (bf16)b.z, (bf16)b.w };
    *(bf16x4*)(Wvb + (size_t)i * 4) = bf16x4{ (bf16)c.x, (bf16)c.y, (bf16)c.z, (bf16)c.w };
    *(bf16x4*)(Wob + (size_t)i * 4) = bf16x4{ (bf16)d.x, (bf16)d.y, (bf16)d.z, (bf16)d.w };
  }
  for (int i = tid; i < SEQN * 32; i += nth) {
    const int s = i >> 5, p = i & 31;
    const float invf = (float)pow(10000.0, -(double)p / 32.0);
    const float ang = (float)s * invf;
    float sv, cv;
    sincosf(ang, &sv, &cv);
    ctab[i] = cv;
    stab[i] = sv;
  }
}

// ---------------------------------------------------------------- QKV gemm
__global__ __launch_bounds__(256) void gemm_qkv(
    const bf16* __restrict__ Xb,
    const bf16* __restrict__ Wqb, const bf16* __restrict__ Wkb, const bf16* __restrict__ Wvb,
    const float* __restrict__ bq, const float* __restrict__ bk, const float* __restrict__ bv,
    const float* __restrict__ ctab, const float* __restrict__ stab,
    bf16* __restrict__ Qb, bf16* __restrict__ Kb, bf16* __restrict__ Vtb)
{
  __shared__ bf16 sA[128 * 32];
  __shared__ bf16 sB[128 * 32];

  const int z = blockIdx.z;
  const bf16* Bm = (z == 0) ? Wqb : (z == 1) ? Wkb : Wvb;
  const float* bias = (z == 0) ? bq : (z == 1) ? bk : bv;

  const int t = threadIdx.x;
  const int lane = t & 63, l15 = lane & 15, g = lane >> 4;
  const int wave = t >> 6, wm = wave >> 1, wn = wave & 1;
  const int tileM = blockIdx.y * 128, tileN = blockIdx.x * 128;

  f32x4 acc[4][4] = {};

  const int srow = t >> 2, schk = t & 3;
  const bf16* gA = Xb + (size_t)(tileM + srow) * DMOD + schk * 8;
  const bf16* gB = Bm + (size_t)(tileN + srow) * DMOD + schk * 8;
  bf16* lA = sA + t * 8;
  bf16* lB = sB + t * 8;

  for (int k0 = 0; k0 < DMOD; k0 += 32) {
    __syncthreads();
    gload_lds16(gA + k0, lA);
    gload_lds16(gA + k0 + 64 * DMOD, lA + 2048);
    gload_lds16(gB + k0, lB);
    gload_lds16(gB + k0 + 64 * DMOD, lB + 2048);
    __syncthreads();
    bf16x8 af[4], bfr[4];
#pragma unroll
    for (int i = 0; i < 4; ++i)
      af[i] = *(const bf16x8*)(sA + (wm * 64 + i * 16 + l15) * 32 + g * 8);
#pragma unroll
    for (int j = 0; j < 4; ++j)
      bfr[j] = *(const bf16x8*)(sB + (wn * 64 + j * 16 + l15) * 32 + g * 8);
#pragma unroll
    for (int i = 0; i < 4; ++i)
#pragma unroll
      for (int j = 0; j < 4; ++j)
        acc[i][j] = __builtin_amdgcn_mfma_f32_16x16x32_bf16(af[i], bfr[j], acc[i][j], 0, 0, 0);
  }

#pragma unroll
  for (int j = 0; j < 4; ++j) {
    const int col = tileN + wn * 64 + j * 16 + l15;
    const float bcol = bias[col];
    const int h = col >> 6, d = col & 63;
#pragma unroll
    for (int i = 0; i < 4; ++i) {
#pragma unroll
      for (int r = 0; r < 4; ++r) {
        const int row = tileM + wm * 64 + i * 16 + g * 4 + r;
        const int b = row >> 11, s = row & (SEQN - 1);
        const float v = acc[i][j][r] + bcol;
        if (z != 2) {
          const int pair = d >> 1;
          const float cv = ctab[s * 32 + pair];
          const float sv = stab[s * 32 + pair];
          const float partner = __shfl_xor(v, 1);
          float rv = (d & 1) ? (partner * sv + v * cv) : (v * cv - partner * sv);
          if (z == 0) rv *= QSCALE_LOG2E;   // fold softmax scale+log2e into Q
          bf16* dst = (z == 0) ? Qb : Kb;
          dst[(((size_t)(b * NHEAD + h)) * SEQN + s) * DHEAD + d] = (bf16)rv;
        } else {
          Vtb[(((size_t)(b * NHEAD + h)) * DHEAD + d) * SEQN + s] = (bf16)v;
        }
      }
    }
  }
}

// ---------------------------------------------------------------- attention
// Barrier-free: 512 blocks (16 qtiles x 32 bh), 4 waves x 32 q-rows.
// K/V B-fragments read directly from global (L1/L2-resident tiles).
// Only LDS use: per-wave P transpose (stride 68 -> conflict-free).
__global__ __launch_bounds__(256) void attn_kernel(
    const bf16* __restrict__ Qb, const bf16* __restrict__ Kb,
    const bf16* __restrict__ Vt, bf16* __restrict__ AO)
{
  __shared__ bf16 sP[4][2][16 * 68];

  const int t = threadIdx.x;
  const int lane = t & 63, l15 = lane & 15, g = lane >> 4;
  const int wave = t >> 6;

  const int bid = blockIdx.x;
  const int qi = bid & 15, bh = bid >> 4;
  // heavy/light interleave: 15,0,14,1,... so any contiguous bid run mixes work
  const int qtile = (qi & 1) ? (qi >> 1) : (15 - (qi >> 1));
  const int q0 = qtile * 128;
  const int qbase = q0 + wave * 32;

  const bf16* Kp = Kb + (size_t)bh * SEQN * DHEAD;
  const bf16* Vp = Vt + (size_t)bh * DHEAD * SEQN;
  const bf16* Qp = Qb + (size_t)bh * SEQN * DHEAD;

  bf16x8 aq[2][2];
#pragma unroll
  for (int qs = 0; qs < 2; ++qs)
#pragma unroll
    for (int kc = 0; kc < 2; ++kc)
      aq[qs][kc] = *(const bf16x8*)(Qp + (size_t)(qbase + qs * 16 + l15) * DHEAD + kc * 32 + g * 8);

  f32x4 acco[2][4] = {};
  float mrow[2][4], lrow[2][4];
#pragma unroll
  for (int qs = 0; qs < 2; ++qs)
#pragma unroll
    for (int r = 0; r < 4; ++r) { mrow[qs][r] = -1e30f; lrow[qs][r] = 0.f; }

  const int kvend = q0 + 128;
  for (int kv0 = 0; kv0 < kvend; kv0 += 64) {
    // ---- K fragments (direct from global; contiguous 16B per lane)
    bf16x8 bk[4][2];
#pragma unroll
    for (int j = 0; j < 4; ++j)
#pragma unroll
      for (int kc = 0; kc < 2; ++kc)
        bk[j][kc] = *(const bf16x8*)(Kp + (size_t)(kv0 + j * 16 + l15) * DHEAD + kc * 32 + g * 8);

    // ---- V fragments issued early so latency hides under QK^T + softmax
    bf16x8 bv[4][2];
#pragma unroll
    for (int j = 0; j < 4; ++j)
#pragma unroll
      for (int kc = 0; kc < 2; ++kc)
        bv[j][kc] = *(const bf16x8*)(Vp + (size_t)(j * 16 + l15) * SEQN + kv0 + kc * 32 + g * 8);

    // ---- QK^T: each K fragment feeds both q-subtiles
    f32x4 sc[2][4] = {};
#pragma unroll
    for (int j = 0; j < 4; ++j)
#pragma unroll
      for (int kc = 0; kc < 2; ++kc) {
#pragma unroll
        for (int qs = 0; qs < 2; ++qs)
          sc[qs][j] = __builtin_amdgcn_mfma_f32_16x16x32_bf16(aq[qs][kc], bk[j][kc], sc[qs][j], 0, 0, 0);
      }

    // ---- softmax per q-subtile (rows g*4+r, cols j*16+l15); log2 domain
#pragma unroll
    for (int qs = 0; qs < 2; ++qs) {
      const int qr = qbase + qs * 16;
      if (kv0 + 63 > qr) {   // diagonal tile: apply causal mask
#pragma unroll
        for (int j = 0; j < 4; ++j) {
          const int kg = kv0 + j * 16 + l15;
#pragma unroll
          for (int r = 0; r < 4; ++r) {
            const int qg = qr + g * 4 + r;
            if (kg > qg) sc[qs][j][r] = -1e30f;
          }
        }
      }
      float p[4][4];
#pragma unroll
      for (int r = 0; r < 4; ++r) {
        float tm = fmaxf(fmaxf(sc[qs][0][r], sc[qs][1][r]), fmaxf(sc[qs][2][r], sc[qs][3][r]));
        tm = fmaxf(tm, __shfl_xor(tm, 1));
        tm = fmaxf(tm, __shfl_xor(tm, 2));
        tm = fmaxf(tm, __shfl_xor(tm, 4));
        tm = fmaxf(tm, __shfl_xor(tm, 8));
        const float mnew = fmaxf(mrow[qs][r], tm);
        const float alpha = __builtin_amdgcn_exp2f(mrow[qs][r] - mnew);
        mrow[qs][r] = mnew;
        float rs = 0.f;
#pragma unroll
        for (int j = 0; j < 4; ++j) {
          const float pv = __builtin_amdgcn_exp2f(sc[qs][j][r] - mnew);
          p[j][r] = pv;
          rs += pv;
        }
        rs += __shfl_xor(rs, 1);
        rs += __shfl_xor(rs, 2);
        rs += __shfl_xor(rs, 4);
        rs += __shfl_xor(rs, 8);
        lrow[qs][r] = lrow[qs][r] * alpha + rs;
#pragma unroll
        for (int j = 0; j < 4; ++j) acco[qs][j][r] *= alpha;
      }
      // P -> per-wave LDS (C-layout -> A-frag layout), stride 68: conflict-free
#pragma unroll
      for (int r = 0; r < 4; ++r)
#pragma unroll
        for (int j = 0; j < 4; ++j)
          sP[wave][qs][(g * 4 + r) * 68 + j * 16 + l15] = (bf16)p[j][r];
    }

    // wave-synchronous LDS: all 64 lanes' writes drain, then read fragments
    asm volatile("s_waitcnt lgkmcnt(0)" ::: "memory");

    bf16x8 pa[2][2];
#pragma unroll
    for (int qs = 0; qs < 2; ++qs)
#pragma unroll
      for (int kc = 0; kc < 2; ++kc)
        pa[qs][kc] = *(const bf16x8*)(&sP[wave][qs][l15 * 68 + kc * 32 + g * 8]);

#pragma unroll
    for (int j = 0; j < 4; ++j)
#pragma unroll
      for (int kc = 0; kc < 2; ++kc) {
#pragma unroll
        for (int qs = 0; qs < 2; ++qs)
          acco[qs][j] = __builtin_amdgcn_mfma_f32_16x16x32_bf16(pa[qs][kc], bv[j][kc], acco[qs][j], 0, 0, 0);
      }
    // next iteration overwrites sP only after these reads complete (in-order
    // lgkmcnt drain precedes the next waitcnt before pa reads)
    asm volatile("s_waitcnt lgkmcnt(0)" ::: "memory");
  }

  const int b = bh >> 4, h = bh & 15;
#pragma unroll
  for (int qs = 0; qs < 2; ++qs)
#pragma unroll
    for (int j = 0; j < 4; ++j)
#pragma unroll
      for (int r = 0; r < 4; ++r) {
        const int q = qbase + qs * 16 + g * 4 + r;
        const int dd = j * 16 + l15;
        const float v = acco[qs][j][r] / lrow[qs][r];
        AO[((size_t)(b * SEQN + q)) * DMOD + h * DHEAD + dd] = (bf16)v;
      }
}

// ---------------------------------------------------------------- out gemm
__global__ __launch_bounds__(256) void gemm_out(
    const bf16* __restrict__ AO, const bf16* __restrict__ Wob,
    const float* __restrict__ bo, float* __restrict__ out)
{
  __shared__ bf16 sA[128 * 32];
  __shared__ bf16 sB[128 * 32];

  const int t = threadIdx.x;
  const int lane = t & 63, l15 = lane & 15, g = lane >> 4;
  const int wave = t >> 6, wm = wave >> 1, wn = wave & 1;
  const int tileM = blockIdx.y * 128, tileN = blockIdx.x * 128;

  f32x4 acc[4][4] = {};

  const int srow = t >> 2, schk = t & 3;
  const bf16* gA = AO + (size_t)(tileM + srow) * DMOD + schk * 8;
  const bf16* gB = Wob + (size_t)(tileN + srow) * DMOD + schk * 8;
  bf16* lA = sA + t * 8;
  bf16* lB = sB + t * 8;

  for (int k0 = 0; k0 < DMOD; k0 += 32) {
    __syncthreads();
    gload_lds16(gA + k0, lA);
    gload_lds16(gA + k0 + 64 * DMOD, lA + 2048);
    gload_lds16(gB + k0, lB);
    gload_lds16(gB + k0 + 64 * DMOD, lB + 2048);
    __syncthreads();
    bf16x8 af[4], bfr[4];
#pragma unroll
    for (int i = 0; i < 4; ++i)
      af[i] = *(const bf16x8*)(sA + (wm * 64 + i * 16 + l15) * 32 + g * 8);
#pragma unroll
    for (int j = 0; j < 4; ++j)
      bfr[j] = *(const bf16x8*)(sB + (wn * 64 + j * 16 + l15) * 32 + g * 8);
#pragma unroll
    for (int i = 0; i < 4; ++i)
#pragma unroll
      for (int j = 0; j < 4; ++j)
        acc[i][j] = __builtin_amdgcn_mfma_f32_16x16x32_bf16(af[i], bfr[j], acc[i][j], 0, 0, 0);
  }

#pragma unroll
  for (int j = 0; j < 4; ++j) {
    const int col = tileN + wn * 64 + j * 16 + l15;
    const float bcol = bo[col];
#pragma unroll
    for (int i = 0; i < 4; ++i)
#pragma unroll
      for (int r = 0; r < 4; ++r) {
        const int row = tileM + wm * 64 + i * 16 + g * 4 + r;
        out[(size_t)row * DMOD + col] = acc[i][j][r] + bcol;
      }
  }
}

// ---------------------------------------------------------------- launch
extern "C" void kernel_launch(void* const* d_in, const int* in_sizes, int n_in,
                              void* d_out, int out_size, void* d_ws, size_t ws_size,
                              hipStream_t stream)
{
  (void)in_sizes; (void)n_in; (void)out_size; (void)ws_size;
  const float* X  = (const float*)d_in[0];
  const float* Wq = (const float*)d_in[1];
  const float* bq = (const float*)d_in[2];
  const float* Wk = (const float*)d_in[3];
  const float* bk = (const float*)d_in[4];
  const float* Wv = (const float*)d_in[5];
  const float* bv = (const float*)d_in[6];
  const float* Wo = (const float*)d_in[7];
  const float* bo = (const float*)d_in[8];

  char* ws = (char*)d_ws;
  float* ctab = (float*)(ws + 0);
  float* stab = (float*)(ws + 262144);
  bf16* Xb  = (bf16*)(ws + 524288);
  bf16* Wqb = (bf16*)(ws + 8912896);
  bf16* Wkb = (bf16*)(ws + 11010048);
  bf16* Wvb = (bf16*)(ws + 13107200);
  bf16* Wob = (bf16*)(ws + 15204352);
  bf16* Qb  = (bf16*)(ws + 17301504);
  bf16* Kb  = (bf16*)(ws + 25690112);
  bf16* Vtb = (bf16*)(ws + 34078720);
  bf16* AO  = (bf16*)(ws + 42467328);

  prep_kernel<<<1024, 256, 0, stream>>>(X, Wq, Wk, Wv, Wo, Xb, Wqb, Wkb, Wvb, Wob, ctab, stab);
  gemm_qkv<<<dim3(8, 32, 3), 256, 0, stream>>>(Xb, Wqb, Wkb, Wvb, bq, bk, bv, ctab, stab, Qb, Kb, Vtb);
  attn_kernel<<<512, 256, 0, stream>>>(Qb, Kb, Vtb, AO);
  gemm_out<<<dim3(8, 32), 256, 0, stream>>>(AO, Wob, bo, (float*)d_out);
}

// Round 3
// 192.483 us; speedup vs baseline: 1.1828x; 1.1792x over previous
//
#include <hip/hip_runtime.h>
#include <hip/hip_bf16.h>
#include <stdint.h>
#include <math.h>

// CausalMultiheadRoPEAttn: B=2, S=2048, D=1024, H=16, Dh=64
// prep (bf16 casts + rope table) -> fused QKV gemm (+bias+rope, V transposed,
// padded stride) -> balanced barrier-free flash attention (paired q-tiles,
// 1 block/CU, register-double-buffered K/V prefetch) -> out gemm.

typedef __bf16 bf16;
typedef __attribute__((ext_vector_type(4))) __bf16 bf16x4;
typedef __attribute__((ext_vector_type(8))) __bf16 bf16x8;
typedef __attribute__((ext_vector_type(4))) float f32x4;

#define SEQN 2048
#define DMOD 1024
#define NHEAD 16
#define DHEAD 64
#define MTOT 4096
#define VSTR 2080   // padded Vt row stride (elements): rotates L2 channels
// 0.125 * log2(e): scores land in log2 domain -> softmax uses exp2
#define QSCALE_LOG2E 0.18033688011112042f

__device__ __forceinline__ void gload_lds16(const bf16* g, bf16* l) {
  __builtin_amdgcn_global_load_lds(
      (const __attribute__((address_space(1))) uint32_t*)g,
      (__attribute__((address_space(3))) uint32_t*)l,
      16, 0, 0);
}

// ---------------------------------------------------------------- prep
__global__ __launch_bounds__(256) void prep_kernel(
    const float* __restrict__ X,
    const float* __restrict__ Wq, const float* __restrict__ Wk,
    const float* __restrict__ Wv, const float* __restrict__ Wo,
    bf16* __restrict__ Xb, bf16* __restrict__ Wqb, bf16* __restrict__ Wkb,
    bf16* __restrict__ Wvb, bf16* __restrict__ Wob,
    float* __restrict__ ctab, float* __restrict__ stab)
{
  const int tid = blockIdx.x * blockDim.x + threadIdx.x;
  const int nth = gridDim.x * blockDim.x;

  const float4* X4 = (const float4*)X;
  for (int i = tid; i < MTOT * DMOD / 4; i += nth) {
    float4 v = X4[i];
    bf16x4 o = { (bf16)v.x, (bf16)v.y, (bf16)v.z, (bf16)v.w };
    *(bf16x4*)(Xb + (size_t)i * 4) = o;
  }
  const float4* q4 = (const float4*)Wq;
  const float4* k4 = (const float4*)Wk;
  const float4* v4 = (const float4*)Wv;
  const float4* o4 = (const float4*)Wo;
  for (int i = tid; i < DMOD * DMOD / 4; i += nth) {
    float4 a = q4[i];
    float4 b = k4[i];
    float4 c = v4[i];
    float4 d = o4[i];
    *(bf16x4*)(Wqb + (size_t)i * 4) = bf16x4{ (bf16)a.x, (bf16)a.y, (bf16)a.z, (bf16)a.w };
    *(bf16x4*)(Wkb + (size_t)i * 4) = bf16x4{ (bf16)b.x, (bf16)b.y, (bf16)b.z, (bf16)b.w };
    *(bf16x4*)(Wvb + (size_t)i * 4) = bf16x4{ (bf16)c.x, (bf16)c.y, (bf16)c.z, (bf16)c.w };
    *(bf16x4*)(Wob + (size_t)i * 4) = bf16x4{ (bf16)d.x, (bf16)d.y, (bf16)d.z, (bf16)d.w };
  }
  for (int i = tid; i < SEQN * 32; i += nth) {
    const int s = i >> 5, p = i & 31;
    const float invf = (float)pow(10000.0, -(double)p / 32.0);
    const float ang = (float)s * invf;
    float sv, cv;
    sincosf(ang, &sv, &cv);
    ctab[i] = cv;
    stab[i] = sv;
  }
}

// ---------------------------------------------------------------- QKV gemm
__global__ __launch_bounds__(256) void gemm_qkv(
    const bf16* __restrict__ Xb,
    const bf16* __restrict__ Wqb, const bf16* __restrict__ Wkb, const bf16* __restrict__ Wvb,
    const float* __restrict__ bq, const float* __restrict__ bk, const float* __restrict__ bv,
    const float* __restrict__ ctab, const float* __restrict__ stab,
    bf16* __restrict__ Qb, bf16* __restrict__ Kb, bf16* __restrict__ Vtb)
{
  __shared__ bf16 sA[128 * 32];
  __shared__ bf16 sB[128 * 32];

  const int z = blockIdx.z;
  const bf16* Bm = (z == 0) ? Wqb : (z == 1) ? Wkb : Wvb;
  const float* bias = (z == 0) ? bq : (z == 1) ? bk : bv;

  const int t = threadIdx.x;
  const int lane = t & 63, l15 = lane & 15, g = lane >> 4;
  const int wave = t >> 6, wm = wave >> 1, wn = wave & 1;
  const int tileM = blockIdx.y * 128, tileN = blockIdx.x * 128;

  f32x4 acc[4][4] = {};

  const int srow = t >> 2, schk = t & 3;
  const bf16* gA = Xb + (size_t)(tileM + srow) * DMOD + schk * 8;
  const bf16* gB = Bm + (size_t)(tileN + srow) * DMOD + schk * 8;
  bf16* lA = sA + t * 8;
  bf16* lB = sB + t * 8;

  for (int k0 = 0; k0 < DMOD; k0 += 32) {
    __syncthreads();
    gload_lds16(gA + k0, lA);
    gload_lds16(gA + k0 + 64 * DMOD, lA + 2048);
    gload_lds16(gB + k0, lB);
    gload_lds16(gB + k0 + 64 * DMOD, lB + 2048);
    __syncthreads();
    bf16x8 af[4], bfr[4];
#pragma unroll
    for (int i = 0; i < 4; ++i)
      af[i] = *(const bf16x8*)(sA + (wm * 64 + i * 16 + l15) * 32 + g * 8);
#pragma unroll
    for (int j = 0; j < 4; ++j)
      bfr[j] = *(const bf16x8*)(sB + (wn * 64 + j * 16 + l15) * 32 + g * 8);
#pragma unroll
    for (int i = 0; i < 4; ++i)
#pragma unroll
      for (int j = 0; j < 4; ++j)
        acc[i][j] = __builtin_amdgcn_mfma_f32_16x16x32_bf16(af[i], bfr[j], acc[i][j], 0, 0, 0);
  }

#pragma unroll
  for (int j = 0; j < 4; ++j) {
    const int col = tileN + wn * 64 + j * 16 + l15;
    const float bcol = bias[col];
    const int h = col >> 6, d = col & 63;
#pragma unroll
    for (int i = 0; i < 4; ++i) {
#pragma unroll
      for (int r = 0; r < 4; ++r) {
        const int row = tileM + wm * 64 + i * 16 + g * 4 + r;
        const int b = row >> 11, s = row & (SEQN - 1);
        const float v = acc[i][j][r] + bcol;
        if (z != 2) {
          const int pair = d >> 1;
          const float cv = ctab[s * 32 + pair];
          const float sv = stab[s * 32 + pair];
          const float partner = __shfl_xor(v, 1);
          float rv = (d & 1) ? (partner * sv + v * cv) : (v * cv - partner * sv);
          if (z == 0) rv *= QSCALE_LOG2E;   // fold softmax scale+log2e into Q
          bf16* dst = (z == 0) ? Qb : Kb;
          dst[(((size_t)(b * NHEAD + h)) * SEQN + s) * DHEAD + d] = (bf16)rv;
        } else {
          Vtb[(((size_t)(b * NHEAD + h)) * DHEAD + d) * VSTR + s] = (bf16)v;
        }
      }
    }
  }
}

// ---------------------------------------------------------------- attention
// 256 blocks (8 qtile-pairs x 32 bh) = exactly 1 block/CU, each block has
// exactly 34 KV-iterations (pair p with 15-p). 4 waves x 32 q-rows.
// K/V fragments read directly from global, register double-buffered so the
// next tile's loads fly under the current tile's compute. No __syncthreads.
__global__ __launch_bounds__(256, 1) void attn_kernel(
    const bf16* __restrict__ Qb, const bf16* __restrict__ Kb,
    const bf16* __restrict__ Vt, bf16* __restrict__ AO)
{
  __shared__ bf16 sP[4][2][16 * 68];

  const int t = threadIdx.x;
  const int lane = t & 63, l15 = lane & 15, g = lane >> 4;
  const int wave = t >> 6;

  const int bid = blockIdx.x;
  const int p = bid & 7, bh = bid >> 3;

  const bf16* Kp = Kb + (size_t)bh * SEQN * DHEAD;
  const bf16* Vp = Vt + (size_t)bh * DHEAD * VSTR;
  const bf16* Qp = Qb + (size_t)bh * SEQN * DHEAD;
  const int b = bh >> 4, h = bh & 15;

  auto prefetch = [&](bf16x8 (&K)[4][2], bf16x8 (&V)[4][2], int kv) {
#pragma unroll
    for (int j = 0; j < 4; ++j)
#pragma unroll
      for (int kc = 0; kc < 2; ++kc) {
        K[j][kc] = *(const bf16x8*)(Kp + (size_t)(kv + j * 16 + l15) * DHEAD + kc * 32 + g * 8);
        V[j][kc] = *(const bf16x8*)(Vp + (size_t)(j * 16 + l15) * VSTR + kv + kc * 32 + g * 8);
      }
  };

  auto run_phase = [&](int qtile) {
    const int q0 = qtile * 128;
    const int qbase = q0 + wave * 32;
    const int kvend = q0 + 128;

    bf16x8 aq[2][2];
#pragma unroll
    for (int qs = 0; qs < 2; ++qs)
#pragma unroll
      for (int kc = 0; kc < 2; ++kc)
        aq[qs][kc] = *(const bf16x8*)(Qp + (size_t)(qbase + qs * 16 + l15) * DHEAD + kc * 32 + g * 8);

    f32x4 acco[2][4] = {};
    float mrow[2][4], lrow[2][4];
#pragma unroll
    for (int qs = 0; qs < 2; ++qs)
#pragma unroll
      for (int r = 0; r < 4; ++r) { mrow[qs][r] = -1e30f; lrow[qs][r] = 0.f; }

    auto compute = [&](const bf16x8 (&K)[4][2], const bf16x8 (&V)[4][2], int kv0) {
      // ---- QK^T
      f32x4 sc[2][4] = {};
#pragma unroll
      for (int j = 0; j < 4; ++j)
#pragma unroll
        for (int kc = 0; kc < 2; ++kc)
#pragma unroll
          for (int qs = 0; qs < 2; ++qs)
            sc[qs][j] = __builtin_amdgcn_mfma_f32_16x16x32_bf16(aq[qs][kc], K[j][kc], sc[qs][j], 0, 0, 0);

      // ---- softmax (rows g*4+r, cols j*16+l15), log2 domain
#pragma unroll
      for (int qs = 0; qs < 2; ++qs) {
        const int qr = qbase + qs * 16;
        if (kv0 + 63 > qr) {   // diagonal tile: causal mask
#pragma unroll
          for (int j = 0; j < 4; ++j) {
            const int kg = kv0 + j * 16 + l15;
#pragma unroll
            for (int r = 0; r < 4; ++r) {
              const int qg = qr + g * 4 + r;
              if (kg > qg) sc[qs][j][r] = -1e30f;
            }
          }
        }
        float pp[4][4];
#pragma unroll
        for (int r = 0; r < 4; ++r) {
          float tm = fmaxf(fmaxf(sc[qs][0][r], sc[qs][1][r]), fmaxf(sc[qs][2][r], sc[qs][3][r]));
          tm = fmaxf(tm, __shfl_xor(tm, 1));
          tm = fmaxf(tm, __shfl_xor(tm, 2));
          tm = fmaxf(tm, __shfl_xor(tm, 4));
          tm = fmaxf(tm, __shfl_xor(tm, 8));
          const float mnew = fmaxf(mrow[qs][r], tm);
          const float alpha = __builtin_amdgcn_exp2f(mrow[qs][r] - mnew);
          mrow[qs][r] = mnew;
          float rs = 0.f;
#pragma unroll
          for (int j = 0; j < 4; ++j) {
            const float pv = __builtin_amdgcn_exp2f(sc[qs][j][r] - mnew);
            pp[j][r] = pv;
            rs += pv;
          }
          rs += __shfl_xor(rs, 1);
          rs += __shfl_xor(rs, 2);
          rs += __shfl_xor(rs, 4);
          rs += __shfl_xor(rs, 8);
          lrow[qs][r] = lrow[qs][r] * alpha + rs;
#pragma unroll
          for (int j = 0; j < 4; ++j) acco[qs][j][r] *= alpha;
        }
        // P -> per-wave LDS (C-layout -> A-frag layout)
#pragma unroll
        for (int r = 0; r < 4; ++r)
#pragma unroll
          for (int j = 0; j < 4; ++j)
            sP[wave][qs][(g * 4 + r) * 68 + j * 16 + l15] = (bf16)pp[j][r];
      }

      asm volatile("s_waitcnt lgkmcnt(0)" ::: "memory");

      bf16x8 pa[2][2];
#pragma unroll
      for (int qs = 0; qs < 2; ++qs)
#pragma unroll
        for (int kc = 0; kc < 2; ++kc)
          pa[qs][kc] = *(const bf16x8*)(&sP[wave][qs][l15 * 68 + kc * 32 + g * 8]);

#pragma unroll
      for (int j = 0; j < 4; ++j)
#pragma unroll
        for (int kc = 0; kc < 2; ++kc)
#pragma unroll
          for (int qs = 0; qs < 2; ++qs)
            acco[qs][j] = __builtin_amdgcn_mfma_f32_16x16x32_bf16(pa[qs][kc], V[j][kc], acco[qs][j], 0, 0, 0);

      asm volatile("s_waitcnt lgkmcnt(0)" ::: "memory");
    };

    bf16x8 kA[4][2], vA[4][2], kB[4][2], vB[4][2];
    prefetch(kA, vA, 0);
    for (int kv0 = 0; kv0 < kvend; kv0 += 128) {
      prefetch(kB, vB, kv0 + 64);                     // always < kvend
      compute(kA, vA, kv0);
      const int nxt = (kv0 + 128 < kvend) ? kv0 + 128 : 0;  // clamp: warm, unused
      prefetch(kA, vA, nxt);
      compute(kB, vB, kv0 + 64);
    }

    // epilogue
#pragma unroll
    for (int qs = 0; qs < 2; ++qs)
#pragma unroll
      for (int j = 0; j < 4; ++j)
#pragma unroll
        for (int r = 0; r < 4; ++r) {
          const int q = qbase + qs * 16 + g * 4 + r;
          const int dd = j * 16 + l15;
          const float v = acco[qs][j][r] / lrow[qs][r];
          AO[((size_t)(b * SEQN + q)) * DMOD + h * DHEAD + dd] = (bf16)v;
        }
  };

  run_phase(p);
  run_phase(15 - p);
}

// ---------------------------------------------------------------- out gemm
__global__ __launch_bounds__(256) void gemm_out(
    const bf16* __restrict__ AO, const bf16* __restrict__ Wob,
    const float* __restrict__ bo, float* __restrict__ out)
{
  __shared__ bf16 sA[128 * 32];
  __shared__ bf16 sB[128 * 32];

  const int t = threadIdx.x;
  const int lane = t & 63, l15 = lane & 15, g = lane >> 4;
  const int wave = t >> 6, wm = wave >> 1, wn = wave & 1;
  const int tileM = blockIdx.y * 128, tileN = blockIdx.x * 128;

  f32x4 acc[4][4] = {};

  const int srow = t >> 2, schk = t & 3;
  const bf16* gA = AO + (size_t)(tileM + srow) * DMOD + schk * 8;
  const bf16* gB = Wob + (size_t)(tileN + srow) * DMOD + schk * 8;
  bf16* lA = sA + t * 8;
  bf16* lB = sB + t * 8;

  for (int k0 = 0; k0 < DMOD; k0 += 32) {
    __syncthreads();
    gload_lds16(gA + k0, lA);
    gload_lds16(gA + k0 + 64 * DMOD, lA + 2048);
    gload_lds16(gB + k0, lB);
    gload_lds16(gB + k0 + 64 * DMOD, lB + 2048);
    __syncthreads();
    bf16x8 af[4], bfr[4];
#pragma unroll
    for (int i = 0; i < 4; ++i)
      af[i] = *(const bf16x8*)(sA + (wm * 64 + i * 16 + l15) * 32 + g * 8);
#pragma unroll
    for (int j = 0; j < 4; ++j)
      bfr[j] = *(const bf16x8*)(sB + (wn * 64 + j * 16 + l15) * 32 + g * 8);
#pragma unroll
    for (int i = 0; i < 4; ++i)
#pragma unroll
      for (int j = 0; j < 4; ++j)
        acc[i][j] = __builtin_amdgcn_mfma_f32_16x16x32_bf16(af[i], bfr[j], acc[i][j], 0, 0, 0);
  }

#pragma unroll
  for (int j = 0; j < 4; ++j) {
    const int col = tileN + wn * 64 + j * 16 + l15;
    const float bcol = bo[col];
#pragma unroll
    for (int i = 0; i < 4; ++i)
#pragma unroll
      for (int r = 0; r < 4; ++r) {
        const int row = tileM + wm * 64 + i * 16 + g * 4 + r;
        out[(size_t)row * DMOD + col] = acc[i][j][r] + bcol;
      }
  }
}

// ---------------------------------------------------------------- launch
extern "C" void kernel_launch(void* const* d_in, const int* in_sizes, int n_in,
                              void* d_out, int out_size, void* d_ws, size_t ws_size,
                              hipStream_t stream)
{
  (void)in_sizes; (void)n_in; (void)out_size; (void)ws_size;
  const float* X  = (const float*)d_in[0];
  const float* Wq = (const float*)d_in[1];
  const float* bq = (const float*)d_in[2];
  const float* Wk = (const float*)d_in[3];
  const float* bk = (const float*)d_in[4];
  const float* Wv = (const float*)d_in[5];
  const float* bv = (const float*)d_in[6];
  const float* Wo = (const float*)d_in[7];
  const float* bo = (const float*)d_in[8];

  char* ws = (char*)d_ws;
  float* ctab = (float*)(ws + 0);
  float* stab = (float*)(ws + 262144);
  bf16* Xb  = (bf16*)(ws + 524288);
  bf16* Wqb = (bf16*)(ws + 8912896);
  bf16* Wkb = (bf16*)(ws + 11010048);
  bf16* Wvb = (bf16*)(ws + 13107200);
  bf16* Wob = (bf16*)(ws + 15204352);
  bf16* Qb  = (bf16*)(ws + 17301504);
  bf16* Kb  = (bf16*)(ws + 25690112);
  bf16* Vtb = (bf16*)(ws + 34078720);   // 32*64*2080*2 = 8519680 bytes
  bf16* AO  = (bf16*)(ws + 42598400);

  prep_kernel<<<1024, 256, 0, stream>>>(X, Wq, Wk, Wv, Wo, Xb, Wqb, Wkb, Wvb, Wob, ctab, stab);
  gemm_qkv<<<dim3(8, 32, 3), 256, 0, stream>>>(Xb, Wqb, Wkb, Wvb, bq, bk, bv, ctab, stab, Qb, Kb, Vtb);
  attn_kernel<<<256, 256, 0, stream>>>(Qb, Kb, Vtb, AO);
  gemm_out<<<dim3(8, 32), 256, 0, stream>>>(AO, Wob, bo, (float*)d_out);
}